// Round 3
// baseline (2119.362 us; speedup 1.0000x reference)
//
#include <hip/hip_runtime.h>
#include <hip/hip_bf16.h>

#define B_ 256
#define D_ 512
#define E_ 512
#define K_ 154

typedef __attribute__((ext_vector_type(8))) short short8;
typedef __attribute__((ext_vector_type(4))) float f32x4;

__device__ __forceinline__ unsigned short f2bf(float f) {
    unsigned u = __float_as_uint(f);
    u = (u + 0x7fffu + ((u >> 16) & 1u)) >> 16;
    return (unsigned short)u;
}

__device__ __forceinline__ f32x4 ldnt4(const float* p) {
    return __builtin_nontemporal_load((const f32x4*)p);
}

// ---------------- kernel 1: gate logits, fp64, LDS-tiled & coalesced -------
__global__ __launch_bounds__(512) void k_gate(const float* __restrict__ x,
                                              const float* __restrict__ gw,
                                              double* __restrict__ logits) {
    const int tg = blockIdx.x;   // 0..31 : 8 tokens
    const int eg = blockIdx.y;   // 0..7  : 64 experts
    const int tid = threadIdx.x;
    const int t0 = tg * 8, e0 = eg * 64;
    __shared__ double xs[8][512];     // 32 KB
    __shared__ float gws[64][65];     // 16.6 KB, +1 pad
    #pragma unroll
    for (int i = 0; i < 8; ++i) {
        int j = i * 512 + tid;
        xs[j >> 9][j & 511] = (double)x[(t0 + (j >> 9)) * D_ + (j & 511)];
    }
    const int e = tid & 63, tl = tid >> 6;
    double acc = 0.0;
    for (int dc = 0; dc < 8; ++dc) {
        __syncthreads();
        #pragma unroll
        for (int i = 0; i < 8; ++i) {
            int j = i * 512 + tid;
            gws[j >> 6][j & 63] = gw[(e0 + (j >> 6)) * D_ + dc * 64 + (j & 63)];
        }
        __syncthreads();
        #pragma unroll 8
        for (int d = 0; d < 64; ++d)
            acc = fma((double)gws[e][d], xs[tl][dc * 64 + d], acc);
    }
    logits[(t0 + tl) * E_ + e0 + e] = acc;
}

// ---------------- kernel 2: exact top-k (rank) + fp64 softmax + x->bf16 ----
__global__ __launch_bounds__(512) void k_topk(const double* __restrict__ logits,
                                              const float* __restrict__ gb,
                                              const float* __restrict__ x,
                                              float* __restrict__ wT,
                                              unsigned short* __restrict__ xb) {
    const int b = blockIdx.x;
    const int e = threadIdx.x;
    __shared__ double vals[E_];
    __shared__ double red[512];
    double v = logits[b * E_ + e] + (double)gb[e];
    vals[e] = v;
    xb[b * D_ + e] = f2bf(x[b * D_ + e]);   // D_ == E_ == 512
    __syncthreads();
    int cnt = 0;
    double m = -1.0e300;
    for (int j = 0; j < E_; ++j) {
        double vj = vals[j];
        m = fmax(m, vj);
        cnt += (vj > v || (vj == v && j < e)) ? 1 : 0;
    }
    double p = (cnt < K_) ? exp(v - m) : 0.0;
    red[e] = p;
    __syncthreads();
    for (int s = 256; s > 0; s >>= 1) {
        if (e < s) red[e] += red[e + s];
        __syncthreads();
    }
    wT[e * B_ + b] = (float)(p / red[0]);
}

// ---------------- kernel 3: main contraction, HBM-streaming MFMA ----------
// grid 1024 = 16 n-tiles(32) x 64 expert-groups(8); block 256 (4 waves).
// TWO=true: plain nontemporal partial stores to P[g]; else atomics to out.
template <bool TWO>
__global__ __launch_bounds__(256, 4) void k_moe(const unsigned short* __restrict__ xb,
                                                const float* __restrict__ wT,
                                                const float* __restrict__ tiles,
                                                float* __restrict__ dst) {
    const int nt = blockIdx.x & 15;
    const int g  = blockIdx.x >> 4;
    const int n0 = nt * 32;
    const int e0 = g * 8;
    const int tid  = threadIdx.x;
    const int wv   = tid >> 6;
    const int lane = tid & 63;
    const int m0   = wv * 64;
    const int quad = lane >> 4;
    const int l16  = lane & 15;

    __shared__ __align__(16) unsigned short Bs[4 * 32 * 72];   // 18 KB
    __shared__ float ws[8][B_];                                // 8 KB

    #pragma unroll
    for (int i = 0; i < 8; ++i) {
        int idx = i * 256 + tid;
        ws[idx >> 8][idx & 255] = wT[(e0 + (idx >> 8)) * B_ + (idx & 255)];
    }

    f32x4 Ct[4][2];
    #pragma unroll
    for (int mi = 0; mi < 4; ++mi)
        #pragma unroll
        for (int ni = 0; ni < 2; ++ni)
            Ct[mi][ni] = (f32x4){0.f, 0.f, 0.f, 0.f};

    for (int kc = 0; kc < 8; ++kc) {
        const int k0 = kc * 64;
        // A fragments held in regs across both expert-phases of this kc
        short8 A[4][2];
        #pragma unroll
        for (int mi = 0; mi < 4; ++mi)
            #pragma unroll
            for (int ks = 0; ks < 2; ++ks)
                A[mi][ks] = *(const short8*)&xb[(m0 + mi * 16 + l16) * D_ + k0 + ks * 32 + quad * 8];

        for (int p = 0; p < 2; ++p) {
            const int ep = e0 + p * 4;
            __syncthreads();   // prior phase's readers done (covers ws, iter 0)
            #pragma unroll
            for (int i = 0; i < 8; ++i) {
                int fi = (i * 256 + tid) * 4;       // float idx in 8192-chunk
                int k  = fi & 63;
                int n  = (fi >> 6) & 31;
                int el = fi >> 11;
                const f32x4 f = ldnt4(tiles + ((ep + el) * D_ + (n0 + n)) * D_ + k0 + k);
                *(ushort4*)&Bs[(el * 32 + n) * 72 + k] =
                    make_ushort4(f2bf(f.x), f2bf(f.y), f2bf(f.z), f2bf(f.w));
            }
            __syncthreads();

            #pragma unroll
            for (int el = 0; el < 4; ++el) {
                f32x4 Ce[4][2];
                #pragma unroll
                for (int mi = 0; mi < 4; ++mi)
                    #pragma unroll
                    for (int ni = 0; ni < 2; ++ni)
                        Ce[mi][ni] = (f32x4){0.f, 0.f, 0.f, 0.f};
                #pragma unroll
                for (int ks = 0; ks < 2; ++ks) {
                    short8 Bf[2];
                    #pragma unroll
                    for (int ni = 0; ni < 2; ++ni)
                        Bf[ni] = *(const short8*)&Bs[(el * 32 + ni * 16 + l16) * 72 + ks * 32 + quad * 8];
                    #pragma unroll
                    for (int mi = 0; mi < 4; ++mi)
                        #pragma unroll
                        for (int ni = 0; ni < 2; ++ni)
                            Ce[mi][ni] = __builtin_amdgcn_mfma_f32_16x16x32_bf16(
                                A[mi][ks], Bf[ni], Ce[mi][ni], 0, 0, 0);
                }
                // C/D layout: col = l16 (n), row = quad*4 + reg
                const float* wrow = ws[p * 4 + el];
                #pragma unroll
                for (int mi = 0; mi < 4; ++mi) {
                    const int rbase = m0 + mi * 16 + quad * 4;
                    float w0 = wrow[rbase + 0], w1 = wrow[rbase + 1];
                    float w2 = wrow[rbase + 2], w3 = wrow[rbase + 3];
                    #pragma unroll
                    for (int ni = 0; ni < 2; ++ni) {
                        Ct[mi][ni].x += w0 * Ce[mi][ni].x;
                        Ct[mi][ni].y += w1 * Ce[mi][ni].y;
                        Ct[mi][ni].z += w2 * Ce[mi][ni].z;
                        Ct[mi][ni].w += w3 * Ce[mi][ni].w;
                    }
                }
            }
        }
    }
    #pragma unroll
    for (int mi = 0; mi < 4; ++mi)
        #pragma unroll
        for (int ni = 0; ni < 2; ++ni) {
            const int row = m0 + mi * 16 + quad * 4;
            const int col = n0 + ni * 16 + l16;
            if (TWO) {
                float* base = dst + ((size_t)g * B_ + row) * D_ + col;
                __builtin_nontemporal_store(Ct[mi][ni].x, base + 0 * D_);
                __builtin_nontemporal_store(Ct[mi][ni].y, base + 1 * D_);
                __builtin_nontemporal_store(Ct[mi][ni].z, base + 2 * D_);
                __builtin_nontemporal_store(Ct[mi][ni].w, base + 3 * D_);
            } else {
                unsafeAtomicAdd(&dst[(row + 0) * D_ + col], Ct[mi][ni].x);
                unsafeAtomicAdd(&dst[(row + 1) * D_ + col], Ct[mi][ni].y);
                unsafeAtomicAdd(&dst[(row + 2) * D_ + col], Ct[mi][ni].z);
                unsafeAtomicAdd(&dst[(row + 3) * D_ + col], Ct[mi][ni].w);
            }
        }
}

// ---------------- kernel 4: sum the 64 partial copies -----------------------
__global__ __launch_bounds__(256) void k_reduce(const float* __restrict__ P,
                                                float* __restrict__ out) {
    const int t = blockIdx.x * 256 + threadIdx.x;   // 0..32767 (float4 idx)
    const f32x4* p4 = (const f32x4*)P;
    f32x4 acc = (f32x4){0.f, 0.f, 0.f, 0.f};
    #pragma unroll 8
    for (int g = 0; g < 64; ++g) {
        f32x4 v = __builtin_nontemporal_load(p4 + (size_t)g * 32768 + t);
        acc.x += v.x; acc.y += v.y; acc.z += v.z; acc.w += v.w;
    }
    ((f32x4*)out)[t] = acc;
}

extern "C" void kernel_launch(void* const* d_in, const int* in_sizes, int n_in,
                              void* d_out, int out_size, void* d_ws, size_t ws_size,
                              hipStream_t stream) {
    const float* x     = (const float*)d_in[0];
    const float* gw    = (const float*)d_in[1];
    const float* gb    = (const float*)d_in[2];
    const float* tiles = (const float*)d_in[3];
    float* out = (float*)d_out;

    // ws layout: logits f64 (1 MB) | wT f32 (512 KB) | xb bf16 (256 KB) | P (32 MB)
    char* base = (char*)d_ws;
    double* logits      = (double*)base;
    float* wT           = (float*)(base + (size_t)B_ * E_ * sizeof(double));
    unsigned short* xb  = (unsigned short*)(base + (size_t)B_ * E_ * (sizeof(double) + sizeof(float)));
    float* P            = (float*)(base + (size_t)B_ * E_ * (sizeof(double) + sizeof(float)) + (size_t)B_ * D_ * 2);
    const size_t need   = (size_t)B_ * E_ * (sizeof(double) + sizeof(float)) + (size_t)B_ * D_ * 2
                        + (size_t)64 * B_ * D_ * sizeof(float);

    k_gate<<<dim3(32, 8), 512, 0, stream>>>(x, gw, logits);
    k_topk<<<256, 512, 0, stream>>>(logits, gb, x, wT, xb);
    if (ws_size >= need) {
        k_moe<true><<<1024, 256, 0, stream>>>(xb, wT, tiles, P);
        k_reduce<<<128, 256, 0, stream>>>(P, out);
    } else {
        hipMemsetAsync(out, 0, (size_t)out_size * sizeof(float), stream);
        k_moe<false><<<1024, 256, 0, stream>>>(xb, wT, tiles, out);
    }
}

// Round 4
// 1061.430 us; speedup vs baseline: 1.9967x; 1.9967x over previous
//
#include <hip/hip_runtime.h>
#include <hip/hip_bf16.h>

#define B_ 256
#define D_ 512
#define E_ 512
#define K_ 154

typedef __attribute__((ext_vector_type(8))) short short8;
typedef __attribute__((ext_vector_type(4))) float f32x4;

__device__ __forceinline__ unsigned short f2bf(float f) {
    unsigned u = __float_as_uint(f);
    u = (u + 0x7fffu + ((u >> 16) & 1u)) >> 16;
    return (unsigned short)u;
}

__device__ __forceinline__ f32x4 ldnt4(const float* p) {
    return __builtin_nontemporal_load((const f32x4*)p);
}

// ---------------- kernel 1: gate logits, fp64, LDS-tiled & coalesced -------
__global__ __launch_bounds__(512) void k_gate(const float* __restrict__ x,
                                              const float* __restrict__ gw,
                                              double* __restrict__ logits) {
    const int tg = blockIdx.x;   // 0..31 : 8 tokens
    const int eg = blockIdx.y;   // 0..7  : 64 experts
    const int tid = threadIdx.x;
    const int t0 = tg * 8, e0 = eg * 64;
    __shared__ double xs[8][512];     // 32 KB
    __shared__ float gws[64][65];     // 16.6 KB, +1 pad
    #pragma unroll
    for (int i = 0; i < 8; ++i) {
        int j = i * 512 + tid;
        xs[j >> 9][j & 511] = (double)x[(t0 + (j >> 9)) * D_ + (j & 511)];
    }
    const int e = tid & 63, tl = tid >> 6;
    double acc = 0.0;
    for (int dc = 0; dc < 8; ++dc) {
        __syncthreads();
        #pragma unroll
        for (int i = 0; i < 8; ++i) {
            int j = i * 512 + tid;
            gws[j >> 6][j & 63] = gw[(e0 + (j >> 6)) * D_ + dc * 64 + (j & 63)];
        }
        __syncthreads();
        #pragma unroll 8
        for (int d = 0; d < 64; ++d)
            acc = fma((double)gws[e][d], xs[tl][dc * 64 + d], acc);
    }
    logits[(t0 + tl) * E_ + e0 + e] = acc;
}

// ---------------- kernel 2: exact top-k (rank) + fp64 softmax + x->bf16 ----
__global__ __launch_bounds__(512) void k_topk(const double* __restrict__ logits,
                                              const float* __restrict__ gb,
                                              const float* __restrict__ x,
                                              float* __restrict__ wT,
                                              unsigned short* __restrict__ xb) {
    const int b = blockIdx.x;
    const int e = threadIdx.x;
    __shared__ double vals[E_];
    __shared__ double red[512];
    double v = logits[b * E_ + e] + (double)gb[e];
    vals[e] = v;
    xb[b * D_ + e] = f2bf(x[b * D_ + e]);   // D_ == E_ == 512
    __syncthreads();
    int cnt = 0;
    double m = -1.0e300;
    for (int j = 0; j < E_; ++j) {
        double vj = vals[j];
        m = fmax(m, vj);
        cnt += (vj > v || (vj == v && j < e)) ? 1 : 0;
    }
    double p = (cnt < K_) ? exp(v - m) : 0.0;
    red[e] = p;
    __syncthreads();
    for (int s = 256; s > 0; s >>= 1) {
        if (e < s) red[e] += red[e + s];
        __syncthreads();
    }
    wT[e * B_ + b] = (float)(p / red[0]);
}

// ---------------- kernel 3: main contraction, HBM-streaming MFMA ----------
// grid 1024 = 16 n-tiles(32) x 64 expert-groups(8); block 256 (4 waves).
// EXACT R2 structure (84 VGPR, no spill). NOTE: (256,3) is the floor — any
// tighter bound (e.g. (256,4)) forces VGPR<=64 and catastrophic spill (R3).
// TWO=true: plain nontemporal partial stores to P[g]; else atomics to dst.
template <bool TWO>
__global__ __launch_bounds__(256, 3) void k_moe(const unsigned short* __restrict__ xb,
                                                const float* __restrict__ wT,
                                                const float* __restrict__ tiles,
                                                float* __restrict__ dst) {
    const int nt = blockIdx.x & 15;
    const int g  = blockIdx.x >> 4;
    const int n0 = nt * 32;
    const int e0 = g * 8;
    const int tid  = threadIdx.x;
    const int wv   = tid >> 6;
    const int lane = tid & 63;
    const int m0   = wv * 64;
    const int quad = lane >> 4;
    const int l16  = lane & 15;

    __shared__ __align__(16) unsigned short Bs[4 * 32 * 72];   // 18 KB
    __shared__ float ws[8][B_];                                // 8 KB

    #pragma unroll
    for (int i = 0; i < 8; ++i) {
        int idx = i * 256 + tid;
        ws[idx >> 8][idx & 255] = wT[(e0 + (idx >> 8)) * B_ + (idx & 255)];
    }

    f32x4 Ct[4][2];
    #pragma unroll
    for (int mi = 0; mi < 4; ++mi)
        #pragma unroll
        for (int ni = 0; ni < 2; ++ni)
            Ct[mi][ni] = (f32x4){0.f, 0.f, 0.f, 0.f};

    for (int p = 0; p < 2; ++p) {
        const int ep = e0 + p * 4;
        for (int kc = 0; kc < 8; ++kc) {
            const int k0 = kc * 64;
            __syncthreads();   // prior chunk's readers done (covers ws, iter 0)
            // stage 4 experts' [32n x 64k] fp32 -> bf16; coalesced, nontemporal
            #pragma unroll
            for (int i = 0; i < 8; ++i) {
                int fi = (i * 256 + tid) * 4;       // float idx in 8192-chunk
                int k  = fi & 63;
                int n  = (fi >> 6) & 31;
                int el = fi >> 11;
                const f32x4 f = ldnt4(tiles + ((ep + el) * D_ + (n0 + n)) * D_ + k0 + k);
                *(ushort4*)&Bs[(el * 32 + n) * 72 + k] =
                    make_ushort4(f2bf(f.x), f2bf(f.y), f2bf(f.z), f2bf(f.w));
            }
            __syncthreads();
            // A fragments direct from L2-resident xb: A[m = l16][k = quad*8 + j]
            short8 A[4][2];
            #pragma unroll
            for (int mi = 0; mi < 4; ++mi)
                #pragma unroll
                for (int ks = 0; ks < 2; ++ks)
                    A[mi][ks] = *(const short8*)&xb[(m0 + mi * 16 + l16) * D_ + k0 + ks * 32 + quad * 8];

            #pragma unroll
            for (int el = 0; el < 4; ++el) {
                f32x4 Ce[4][2];
                #pragma unroll
                for (int mi = 0; mi < 4; ++mi)
                    #pragma unroll
                    for (int ni = 0; ni < 2; ++ni)
                        Ce[mi][ni] = (f32x4){0.f, 0.f, 0.f, 0.f};
                #pragma unroll
                for (int ks = 0; ks < 2; ++ks) {
                    short8 Bf[2];
                    #pragma unroll
                    for (int ni = 0; ni < 2; ++ni)
                        Bf[ni] = *(const short8*)&Bs[(el * 32 + ni * 16 + l16) * 72 + ks * 32 + quad * 8];
                    #pragma unroll
                    for (int mi = 0; mi < 4; ++mi)
                        #pragma unroll
                        for (int ni = 0; ni < 2; ++ni)
                            Ce[mi][ni] = __builtin_amdgcn_mfma_f32_16x16x32_bf16(
                                A[mi][ks], Bf[ni], Ce[mi][ni], 0, 0, 0);
                }
                // C/D layout: col = l16 (n), row = quad*4 + reg
                const float* wrow = ws[p * 4 + el];
                #pragma unroll
                for (int mi = 0; mi < 4; ++mi) {
                    const int rbase = m0 + mi * 16 + quad * 4;
                    float w0 = wrow[rbase + 0], w1 = wrow[rbase + 1];
                    float w2 = wrow[rbase + 2], w3 = wrow[rbase + 3];
                    #pragma unroll
                    for (int ni = 0; ni < 2; ++ni) {
                        Ct[mi][ni].x += w0 * Ce[mi][ni].x;
                        Ct[mi][ni].y += w1 * Ce[mi][ni].y;
                        Ct[mi][ni].z += w2 * Ce[mi][ni].z;
                        Ct[mi][ni].w += w3 * Ce[mi][ni].w;
                    }
                }
            }
        }
    }
    #pragma unroll
    for (int mi = 0; mi < 4; ++mi)
        #pragma unroll
        for (int ni = 0; ni < 2; ++ni) {
            const int row = m0 + mi * 16 + quad * 4;
            const int col = n0 + ni * 16 + l16;
            if (TWO) {
                float* base = dst + ((size_t)g * B_ + row) * D_ + col;
                __builtin_nontemporal_store(Ct[mi][ni].x, base + 0 * D_);
                __builtin_nontemporal_store(Ct[mi][ni].y, base + 1 * D_);
                __builtin_nontemporal_store(Ct[mi][ni].z, base + 2 * D_);
                __builtin_nontemporal_store(Ct[mi][ni].w, base + 3 * D_);
            } else {
                unsafeAtomicAdd(&dst[(row + 0) * D_ + col], Ct[mi][ni].x);
                unsafeAtomicAdd(&dst[(row + 1) * D_ + col], Ct[mi][ni].y);
                unsafeAtomicAdd(&dst[(row + 2) * D_ + col], Ct[mi][ni].z);
                unsafeAtomicAdd(&dst[(row + 3) * D_ + col], Ct[mi][ni].w);
            }
        }
}

// ---------------- kernel 4: sum the 64 partial copies -----------------------
__global__ __launch_bounds__(256) void k_reduce(const float* __restrict__ P,
                                                float* __restrict__ out) {
    const int t = blockIdx.x * 256 + threadIdx.x;   // 0..32767 (float4 idx)
    const f32x4* p4 = (const f32x4*)P;
    f32x4 acc = (f32x4){0.f, 0.f, 0.f, 0.f};
    #pragma unroll 8
    for (int g = 0; g < 64; ++g) {
        f32x4 v = __builtin_nontemporal_load(p4 + (size_t)g * 32768 + t);
        acc.x += v.x; acc.y += v.y; acc.z += v.z; acc.w += v.w;
    }
    ((f32x4*)out)[t] = acc;
}

extern "C" void kernel_launch(void* const* d_in, const int* in_sizes, int n_in,
                              void* d_out, int out_size, void* d_ws, size_t ws_size,
                              hipStream_t stream) {
    const float* x     = (const float*)d_in[0];
    const float* gw    = (const float*)d_in[1];
    const float* gb    = (const float*)d_in[2];
    const float* tiles = (const float*)d_in[3];
    float* out = (float*)d_out;

    // ws layout: logits f64 (1 MB) | wT f32 (512 KB) | xb bf16 (256 KB) | P (32 MB)
    char* base = (char*)d_ws;
    double* logits      = (double*)base;
    float* wT           = (float*)(base + (size_t)B_ * E_ * sizeof(double));
    unsigned short* xb  = (unsigned short*)(base + (size_t)B_ * E_ * (sizeof(double) + sizeof(float)));
    float* P            = (float*)(base + (size_t)B_ * E_ * (sizeof(double) + sizeof(float)) + (size_t)B_ * D_ * 2);
    const size_t need   = (size_t)B_ * E_ * (sizeof(double) + sizeof(float)) + (size_t)B_ * D_ * 2
                        + (size_t)64 * B_ * D_ * sizeof(float);

    k_gate<<<dim3(32, 8), 512, 0, stream>>>(x, gw, logits);
    k_topk<<<256, 512, 0, stream>>>(logits, gb, x, wT, xb);
    if (ws_size >= need) {
        k_moe<true><<<1024, 256, 0, stream>>>(xb, wT, tiles, P);
        k_reduce<<<128, 256, 0, stream>>>(P, out);
    } else {
        hipMemsetAsync(out, 0, (size_t)out_size * sizeof(float), stream);
        k_moe<false><<<1024, 256, 0, stream>>>(xb, wT, tiles, out);
    }
}

// Round 5
// 914.753 us; speedup vs baseline: 2.3169x; 1.1603x over previous
//
#include <hip/hip_runtime.h>
#include <hip/hip_bf16.h>

#define B_ 256
#define D_ 512
#define E_ 512
#define K_ 154

typedef __attribute__((ext_vector_type(8))) short short8;
typedef __attribute__((ext_vector_type(4))) float f32x4;

__device__ __forceinline__ unsigned short f2bf(float f) {
    unsigned u = __float_as_uint(f);
    u = (u + 0x7fffu + ((u >> 16) & 1u)) >> 16;
    return (unsigned short)u;
}

__device__ __forceinline__ f32x4 ldnt4(const float* p) {
    return __builtin_nontemporal_load((const f32x4*)p);
}

// ---------------- kernel 1: gate logits, fp64, LDS-tiled & coalesced -------
__global__ __launch_bounds__(512) void k_gate(const float* __restrict__ x,
                                              const float* __restrict__ gw,
                                              double* __restrict__ logits) {
    const int tg = blockIdx.x;   // 0..31 : 8 tokens
    const int eg = blockIdx.y;   // 0..7  : 64 experts
    const int tid = threadIdx.x;
    const int t0 = tg * 8, e0 = eg * 64;
    __shared__ double xs[8][512];     // 32 KB
    __shared__ float gws[64][65];     // 16.6 KB, +1 pad
    #pragma unroll
    for (int i = 0; i < 8; ++i) {
        int j = i * 512 + tid;
        xs[j >> 9][j & 511] = (double)x[(t0 + (j >> 9)) * D_ + (j & 511)];
    }
    const int e = tid & 63, tl = tid >> 6;
    double acc = 0.0;
    for (int dc = 0; dc < 8; ++dc) {
        __syncthreads();
        #pragma unroll
        for (int i = 0; i < 8; ++i) {
            int j = i * 512 + tid;
            gws[j >> 6][j & 63] = gw[(e0 + (j >> 6)) * D_ + dc * 64 + (j & 63)];
        }
        __syncthreads();
        #pragma unroll 8
        for (int d = 0; d < 64; ++d)
            acc = fma((double)gws[e][d], xs[tl][dc * 64 + d], acc);
    }
    logits[(t0 + tl) * E_ + e0 + e] = acc;
}

// ---------------- kernel 2: exact top-k (rank) + fp64 softmax + x->bf16 ----
__global__ __launch_bounds__(512) void k_topk(const double* __restrict__ logits,
                                              const float* __restrict__ gb,
                                              const float* __restrict__ x,
                                              float* __restrict__ wT,
                                              unsigned short* __restrict__ xb) {
    const int b = blockIdx.x;
    const int e = threadIdx.x;
    __shared__ double vals[E_];
    __shared__ double red[512];
    double v = logits[b * E_ + e] + (double)gb[e];
    vals[e] = v;
    xb[b * D_ + e] = f2bf(x[b * D_ + e]);   // D_ == E_ == 512
    __syncthreads();
    int cnt = 0;
    double m = -1.0e300;
    for (int j = 0; j < E_; ++j) {
        double vj = vals[j];
        m = fmax(m, vj);
        cnt += (vj > v || (vj == v && j < e)) ? 1 : 0;
    }
    double p = (cnt < K_) ? exp(v - m) : 0.0;
    red[e] = p;
    __syncthreads();
    for (int s = 256; s > 0; s >>= 1) {
        if (e < s) red[e] += red[e + s];
        __syncthreads();
    }
    wT[e * B_ + b] = (float)(p / red[0]);
}

// ---------------- kernel 3: main contraction, HBM-streaming MFMA ----------
// grid = 16 n-tiles(32) x (512/EPG) expert-groups; block 256 (4 waves).
// NOTE: (256,3) is the floor — (256,4) forces VGPR<=64 and catastrophic
// spill (R3). kc-outer: A-frags loaded once per kc, reused over EPG/4 phases.
// TWO=true: plain nontemporal partial stores to P[g]; else atomics to dst.
template <int EPG, bool TWO>
__global__ __launch_bounds__(256, 3) void k_moe(const unsigned short* __restrict__ xb,
                                                const float* __restrict__ wT,
                                                const float* __restrict__ tiles,
                                                float* __restrict__ dst) {
    const int nt = blockIdx.x & 15;
    const int g  = blockIdx.x >> 4;
    const int n0 = nt * 32;
    const int e0 = g * EPG;
    const int tid  = threadIdx.x;
    const int wv   = tid >> 6;
    const int lane = tid & 63;
    const int m0   = wv * 64;
    const int quad = lane >> 4;
    const int l16  = lane & 15;

    __shared__ __align__(16) unsigned short Bs[4 * 32 * 72];   // 18 KB
    __shared__ float ws[EPG][B_];                              // EPG KB

    #pragma unroll
    for (int i = 0; i < EPG; ++i) {
        int idx = i * 256 + tid;
        ws[idx >> 8][idx & 255] = wT[(e0 + (idx >> 8)) * B_ + (idx & 255)];
    }

    f32x4 Ct[4][2];
    #pragma unroll
    for (int mi = 0; mi < 4; ++mi)
        #pragma unroll
        for (int ni = 0; ni < 2; ++ni)
            Ct[mi][ni] = (f32x4){0.f, 0.f, 0.f, 0.f};

    for (int kc = 0; kc < 8; ++kc) {
        const int k0 = kc * 64;
        // A fragments loaded once per kc, reused over all EPG/4 phases
        short8 A[4][2];
        #pragma unroll
        for (int mi = 0; mi < 4; ++mi)
            #pragma unroll
            for (int ks = 0; ks < 2; ++ks)
                A[mi][ks] = *(const short8*)&xb[(m0 + mi * 16 + l16) * D_ + k0 + ks * 32 + quad * 8];

        for (int p = 0; p < EPG / 4; ++p) {
            const int ep = e0 + p * 4;
            __syncthreads();   // prior phase's readers done (covers ws, iter 0)
            // stage 4 experts' [32n x 64k] fp32 -> bf16; coalesced, nontemporal
            #pragma unroll
            for (int i = 0; i < 8; ++i) {
                int fi = (i * 256 + tid) * 4;       // float idx in 8192-chunk
                int k  = fi & 63;
                int n  = (fi >> 6) & 31;
                int el = fi >> 11;
                const f32x4 f = ldnt4(tiles + ((ep + el) * D_ + (n0 + n)) * D_ + k0 + k);
                *(ushort4*)&Bs[(el * 32 + n) * 72 + k] =
                    make_ushort4(f2bf(f.x), f2bf(f.y), f2bf(f.z), f2bf(f.w));
            }
            __syncthreads();

            #pragma unroll
            for (int el = 0; el < 4; ++el) {
                f32x4 Ce[4][2];
                #pragma unroll
                for (int mi = 0; mi < 4; ++mi)
                    #pragma unroll
                    for (int ni = 0; ni < 2; ++ni)
                        Ce[mi][ni] = (f32x4){0.f, 0.f, 0.f, 0.f};
                #pragma unroll
                for (int ks = 0; ks < 2; ++ks) {
                    short8 Bf[2];
                    #pragma unroll
                    for (int ni = 0; ni < 2; ++ni)
                        Bf[ni] = *(const short8*)&Bs[(el * 32 + ni * 16 + l16) * 72 + ks * 32 + quad * 8];
                    #pragma unroll
                    for (int mi = 0; mi < 4; ++mi)
                        #pragma unroll
                        for (int ni = 0; ni < 2; ++ni)
                            Ce[mi][ni] = __builtin_amdgcn_mfma_f32_16x16x32_bf16(
                                A[mi][ks], Bf[ni], Ce[mi][ni], 0, 0, 0);
                }
                // C/D layout: col = l16 (n), row = quad*4 + reg
                const float* wrow = ws[p * 4 + el];
                #pragma unroll
                for (int mi = 0; mi < 4; ++mi) {
                    const int rbase = m0 + mi * 16 + quad * 4;
                    float w0 = wrow[rbase + 0], w1 = wrow[rbase + 1];
                    float w2 = wrow[rbase + 2], w3 = wrow[rbase + 3];
                    #pragma unroll
                    for (int ni = 0; ni < 2; ++ni) {
                        Ct[mi][ni].x += w0 * Ce[mi][ni].x;
                        Ct[mi][ni].y += w1 * Ce[mi][ni].y;
                        Ct[mi][ni].z += w2 * Ce[mi][ni].z;
                        Ct[mi][ni].w += w3 * Ce[mi][ni].w;
                    }
                }
            }
        }
    }
    #pragma unroll
    for (int mi = 0; mi < 4; ++mi)
        #pragma unroll
        for (int ni = 0; ni < 2; ++ni) {
            const int row = m0 + mi * 16 + quad * 4;
            const int col = n0 + ni * 16 + l16;
            if (TWO) {
                float* base = dst + ((size_t)g * B_ + row) * D_ + col;
                __builtin_nontemporal_store(Ct[mi][ni].x, base + 0 * D_);
                __builtin_nontemporal_store(Ct[mi][ni].y, base + 1 * D_);
                __builtin_nontemporal_store(Ct[mi][ni].z, base + 2 * D_);
                __builtin_nontemporal_store(Ct[mi][ni].w, base + 3 * D_);
            } else {
                unsafeAtomicAdd(&dst[(row + 0) * D_ + col], Ct[mi][ni].x);
                unsafeAtomicAdd(&dst[(row + 1) * D_ + col], Ct[mi][ni].y);
                unsafeAtomicAdd(&dst[(row + 2) * D_ + col], Ct[mi][ni].z);
                unsafeAtomicAdd(&dst[(row + 3) * D_ + col], Ct[mi][ni].w);
            }
        }
}

// ---------------- kernel 4: sum the NG partial copies -----------------------
template <int NG>
__global__ __launch_bounds__(256) void k_reduce(const float* __restrict__ P,
                                                float* __restrict__ out) {
    const int t = blockIdx.x * 256 + threadIdx.x;   // 0..32767 (float4 idx)
    const f32x4* p4 = (const f32x4*)P;
    f32x4 acc = (f32x4){0.f, 0.f, 0.f, 0.f};
    #pragma unroll 8
    for (int gidx = 0; gidx < NG; ++gidx) {
        f32x4 v = __builtin_nontemporal_load(p4 + (size_t)gidx * 32768 + t);
        acc.x += v.x; acc.y += v.y; acc.z += v.z; acc.w += v.w;
    }
    ((f32x4*)out)[t] = acc;
}

extern "C" void kernel_launch(void* const* d_in, const int* in_sizes, int n_in,
                              void* d_out, int out_size, void* d_ws, size_t ws_size,
                              hipStream_t stream) {
    const float* x     = (const float*)d_in[0];
    const float* gw    = (const float*)d_in[1];
    const float* gb    = (const float*)d_in[2];
    const float* tiles = (const float*)d_in[3];
    float* out = (float*)d_out;

    // ws layout: xb bf16 (256 KB) | wT f32 (512 KB) | { logits f64 (1 MB) / P }
    // P aliases logits: logits are dead once k_topk finishes.
    char* base = (char*)d_ws;
    unsigned short* xb  = (unsigned short*)base;
    float* wT           = (float*)(base + 262144);
    double* logits      = (double*)(base + 262144 + 524288);
    float* P            = (float*)(base + 262144 + 524288);
    const size_t fixed  = 262144 + 524288;                       // xb + wT
    const size_t slot   = (size_t)B_ * D_ * sizeof(float);       // 512 KB
    const size_t need16 = fixed + 32 * slot;                     // ~16.75 MiB
    const size_t need32 = fixed + 16 * slot;                     // ~8.75 MiB

    k_gate<<<dim3(32, 8), 512, 0, stream>>>(x, gw, logits);
    k_topk<<<256, 512, 0, stream>>>(logits, gb, x, wT, xb);
    if (ws_size >= need16) {
        k_moe<16, true><<<512, 256, 0, stream>>>(xb, wT, tiles, P);
        k_reduce<32><<<128, 256, 0, stream>>>(P, out);
    } else if (ws_size >= need32) {
        k_moe<32, true><<<256, 256, 0, stream>>>(xb, wT, tiles, P);
        k_reduce<16><<<128, 256, 0, stream>>>(P, out);
    } else {
        hipMemsetAsync(out, 0, (size_t)out_size * sizeof(float), stream);
        k_moe<8, false><<<1024, 256, 0, stream>>>(xb, wT, tiles, out);
    }
}